// Round 1
// baseline (1334.468 us; speedup 1.0000x reference)
//
#include <hip/hip_runtime.h>

#define EPS 1e-5f

// ---------------- ws layout (bytes) ----------------
// P    : 20000*128*4 = 10,240,000      @ 0
// W1T  : 128*128*4   = 65,536          @ 10,240,000
// WfT  : 256*128*4   = 131,072         @ 10,305,536
// WaT  : 80*128*4    = 40,960          @ 10,436,608
// tmp  : 500000*128*4= 256,000,000     @ 16,777,216
// total ~273 MB

// ---------------- transpose weights into ws ----------------
__global__ void transpose_w(const float* __restrict__ W1, const float* __restrict__ Wf,
                            const float* __restrict__ Wa,
                            float* __restrict__ W1T, float* __restrict__ WfT,
                            float* __restrict__ WaT) {
    int i = blockIdx.x * 256 + threadIdx.x;
    if (i < 128 * 128) {
        int k = i >> 7, c = i & 127;
        W1T[i] = W1[c * 128 + k];          // W1T[k][c] = W1[c][k]
    } else if (i < 128 * 128 + 256 * 128) {
        int j = i - 128 * 128;
        int k = j >> 7, c = j & 127;
        WfT[j] = Wf[c * 256 + k];          // WfT[k][c] = Wf[c][k], k in [0,256)
    } else if (i < 128 * 128 + 256 * 128 + 80 * 128) {
        int l = i - 128 * 128 - 256 * 128;
        int k = l >> 7, c = l & 127;
        WaT[l] = Wa[c * 80 + k];           // WaT[k][c] = Wa[c][k], k in [0,80)
    }
}

// ---------------- P = agt_x @ Wa^T  [A x 128], K=80 ----------------
__global__ __launch_bounds__(256) void proj_agents(const float* __restrict__ agt,
                                                   const float* __restrict__ WaT,
                                                   float* __restrict__ P) {
    __shared__ float WT[80 * 128];   // 40 KB
    __shared__ float xT[80][32];     // 10 KB, xT[k][r]
    int t = threadIdx.x;
    int row0 = blockIdx.x * 32;
#pragma unroll
    for (int m = 0; m < 40; ++m) WT[t + 256 * m] = WaT[t + 256 * m];
#pragma unroll
    for (int m = 0; m < 10; ++m) {
        int f = t + 256 * m;         // < 2560
        int r = f / 80, k = f - r * 80;
        xT[k][r] = agt[(size_t)(row0 + r) * 80 + k];
    }
    __syncthreads();
    int tx = t & 31, ty = t >> 5;
    float acc[4][4] = {};
    for (int k = 0; k < 80; ++k) {
        float4 xv = *(const float4*)&xT[k][ty * 4];
        float4 wv = *(const float4*)&WT[k * 128 + tx * 4];
        float xa[4] = {xv.x, xv.y, xv.z, xv.w};
        float wa[4] = {wv.x, wv.y, wv.z, wv.w};
#pragma unroll
        for (int i = 0; i < 4; ++i)
#pragma unroll
            for (int j = 0; j < 4; ++j) acc[i][j] = fmaf(xa[i], wa[j], acc[i][j]);
    }
#pragma unroll
    for (int i = 0; i < 4; ++i) {
        int r = row0 + ty * 4 + i;
        float4 o = make_float4(acc[i][0], acc[i][1], acc[i][2], acc[i][3]);
        *(float4*)&P[(size_t)r * 128 + tx * 4] = o;
    }
}

// ---------------- scatter: tmp[v[e]] += P[u[e]] ----------------
__global__ void scatter_msg(const float* __restrict__ P, const int* __restrict__ u,
                            const int* __restrict__ v, float* __restrict__ tmp, int E) {
    long long idx = (long long)blockIdx.x * 256 + threadIdx.x;
    int e = (int)(idx >> 7);
    int c = (int)(idx & 127);
    if (e < E) {
        int a = u[e], n = v[e];
        atomicAdd(&tmp[(size_t)n * 128 + c], P[(size_t)a * 128 + c]);
    }
}

// ---------------- map_fc fused: h = relu(gn(relu(x@W0^T+b0) @ W1^T)) ----------------
__global__ __launch_bounds__(256) void map_fc(const float* __restrict__ mapx,
                                              const float* __restrict__ W0,
                                              const float* __restrict__ b0,
                                              const float* __restrict__ W1T,
                                              const float* __restrict__ g1,
                                              const float* __restrict__ b1,
                                              float* __restrict__ h) {
    __shared__ float h0T[128][32];   // 16 KB, h0T[k][r]
    __shared__ float Wc[64 * 128];   // 32 KB, k-chunk of W1T
    __shared__ float mx[32][9];      // padded: (9r+j) mod 32 hits all banks
    __shared__ float w0s[128][8];
    __shared__ float b0s[128];
    int t = threadIdx.x;
    int row0 = blockIdx.x * 32;
    { int r = t >> 3, j = t & 7; mx[r][j] = mapx[(size_t)(row0 + r) * 8 + j]; }
#pragma unroll
    for (int m = 0; m < 4; ++m) { int f = t + 256 * m; w0s[f >> 3][f & 7] = W0[f]; }
    if (t < 128) b0s[t] = b0[t];
    __syncthreads();
    // GEMM1 (K=8) -> h0T in LDS
#pragma unroll
    for (int m = 0; m < 16; ++m) {
        int f = t + 256 * m;         // 4096 = 128*32
        int r = f & 31, k = f >> 5;
        float a = b0s[k];
#pragma unroll
        for (int j = 0; j < 8; ++j) a = fmaf(mx[r][j], w0s[k][j], a);
        h0T[k][r] = fmaxf(a, 0.f);
    }
    int tx = t & 31, ty = t >> 5;
    float acc[4][4] = {};
    for (int kc = 0; kc < 2; ++kc) {
        __syncthreads();             // protects h0T (kc=0) and Wc re-fill (kc=1)
#pragma unroll
        for (int m = 0; m < 32; ++m) Wc[t + 256 * m] = W1T[kc * 8192 + t + 256 * m];
        __syncthreads();
        for (int kk = 0; kk < 64; ++kk) {
            int k = kc * 64 + kk;
            float4 xv = *(const float4*)&h0T[k][ty * 4];
            float4 wv = *(const float4*)&Wc[kk * 128 + tx * 4];
            float xa[4] = {xv.x, xv.y, xv.z, xv.w};
            float wa[4] = {wv.x, wv.y, wv.z, wv.w};
#pragma unroll
            for (int i = 0; i < 4; ++i)
#pragma unroll
                for (int j = 0; j < 4; ++j) acc[i][j] = fmaf(xa[i], wa[j], acc[i][j]);
        }
    }
    // GN(128ch) + ReLU epilogue; 32 tx-lanes hold 4 ch each per row
    float4 gv = *(const float4*)&g1[tx * 4];
    float4 bv = *(const float4*)&b1[tx * 4];
#pragma unroll
    for (int i = 0; i < 4; ++i) {
        float s1 = acc[i][0] + acc[i][1] + acc[i][2] + acc[i][3];
        float s2 = acc[i][0] * acc[i][0] + acc[i][1] * acc[i][1] +
                   acc[i][2] * acc[i][2] + acc[i][3] * acc[i][3];
#pragma unroll
        for (int m = 1; m < 32; m <<= 1) {   // xor masks <32: stays within tx half-wave
            s1 += __shfl_xor(s1, m, 64);
            s2 += __shfl_xor(s2, m, 64);
        }
        float mean = s1 * (1.f / 128.f);
        float var = s2 * (1.f / 128.f) - mean * mean;
        float inv = rsqrtf(var + EPS);
        int r = row0 + ty * 4 + i;
        float4 o;
        o.x = fmaxf((acc[i][0] - mean) * inv * gv.x + bv.x, 0.f);
        o.y = fmaxf((acc[i][1] - mean) * inv * gv.y + bv.y, 0.f);
        o.z = fmaxf((acc[i][2] - mean) * inv * gv.z + bv.z, 0.f);
        o.w = fmaxf((acc[i][3] - mean) * inv * gv.w + bv.w, 0.f);
        *(float4*)&h[(size_t)r * 128 + tx * 4] = o;
    }
}

// ---------------- final: out = relu(gn(cat[h, relu(gn(tmp))] @ Wf^T)) ----------------
__global__ __launch_bounds__(256) void final_fc(const float* hbuf,
                                                const float* __restrict__ tmp,
                                                const float* __restrict__ g_bn,
                                                const float* __restrict__ b_bn,
                                                const float* __restrict__ WfT,
                                                const float* __restrict__ g_fc,
                                                const float* __restrict__ b_fc,
                                                float* out) {
    __shared__ float catT[256][32];  // 32 KB, catT[k][r]
    __shared__ float Wc[64 * 128];   // 32 KB
    int t = threadIdx.x;
    int row0 = blockIdx.x * 32;
    int r = t >> 3, c0 = (t & 7) * 16;
    {   // stage h rows (transposed)
        const float* src = &hbuf[(size_t)(row0 + r) * 128 + c0];
#pragma unroll
        for (int q = 0; q < 4; ++q) {
            float4 vv = *(const float4*)&src[q * 4];
            catT[c0 + q * 4 + 0][r] = vv.x;
            catT[c0 + q * 4 + 1][r] = vv.y;
            catT[c0 + q * 4 + 2][r] = vv.z;
            catT[c0 + q * 4 + 3][r] = vv.w;
        }
    }
    {   // stage tmp rows with GN+ReLU applied (8 lanes per row reduce 128 ch)
        const float* src = &tmp[(size_t)(row0 + r) * 128 + c0];
        float vals[16];
        float s1 = 0.f, s2 = 0.f;
#pragma unroll
        for (int q = 0; q < 4; ++q) {
            float4 vv = *(const float4*)&src[q * 4];
            vals[q * 4 + 0] = vv.x; vals[q * 4 + 1] = vv.y;
            vals[q * 4 + 2] = vv.z; vals[q * 4 + 3] = vv.w;
        }
#pragma unroll
        for (int q = 0; q < 16; ++q) { s1 += vals[q]; s2 += vals[q] * vals[q]; }
#pragma unroll
        for (int m = 1; m < 8; m <<= 1) {  // reduce across the 8 lanes sharing row r
            s1 += __shfl_xor(s1, m, 64);
            s2 += __shfl_xor(s2, m, 64);
        }
        float mean = s1 * (1.f / 128.f);
        float var = s2 * (1.f / 128.f) - mean * mean;
        float inv = rsqrtf(var + EPS);
#pragma unroll
        for (int q = 0; q < 16; ++q) {
            int c = c0 + q;
            float nv = fmaxf((vals[q] - mean) * inv * g_bn[c] + b_bn[c], 0.f);
            catT[128 + c][r] = nv;
        }
    }
    int tx = t & 31, ty = t >> 5;
    float acc[4][4] = {};
    for (int kc = 0; kc < 4; ++kc) {
        __syncthreads();             // covers catT stage (kc=0) and Wc reuse
#pragma unroll
        for (int m = 0; m < 32; ++m) Wc[t + 256 * m] = WfT[kc * 8192 + t + 256 * m];
        __syncthreads();
        for (int kk = 0; kk < 64; ++kk) {
            float4 xv = *(const float4*)&catT[kc * 64 + kk][ty * 4];
            float4 wv = *(const float4*)&Wc[kk * 128 + tx * 4];
            float xa[4] = {xv.x, xv.y, xv.z, xv.w};
            float wa[4] = {wv.x, wv.y, wv.z, wv.w};
#pragma unroll
            for (int i = 0; i < 4; ++i)
#pragma unroll
                for (int j = 0; j < 4; ++j) acc[i][j] = fmaf(xa[i], wa[j], acc[i][j]);
        }
    }
    float4 gv = *(const float4*)&g_fc[tx * 4];
    float4 bv = *(const float4*)&b_fc[tx * 4];
#pragma unroll
    for (int i = 0; i < 4; ++i) {
        float s1 = acc[i][0] + acc[i][1] + acc[i][2] + acc[i][3];
        float s2 = acc[i][0] * acc[i][0] + acc[i][1] * acc[i][1] +
                   acc[i][2] * acc[i][2] + acc[i][3] * acc[i][3];
#pragma unroll
        for (int m = 1; m < 32; m <<= 1) {
            s1 += __shfl_xor(s1, m, 64);
            s2 += __shfl_xor(s2, m, 64);
        }
        float mean = s1 * (1.f / 128.f);
        float var = s2 * (1.f / 128.f) - mean * mean;
        float inv = rsqrtf(var + EPS);
        int rr = row0 + ty * 4 + i;
        float4 o;
        o.x = fmaxf((acc[i][0] - mean) * inv * gv.x + bv.x, 0.f);
        o.y = fmaxf((acc[i][1] - mean) * inv * gv.y + bv.y, 0.f);
        o.z = fmaxf((acc[i][2] - mean) * inv * gv.z + bv.z, 0.f);
        o.w = fmaxf((acc[i][3] - mean) * inv * gv.w + bv.w, 0.f);
        *(float4*)&out[(size_t)rr * 128 + tx * 4] = o;
    }
}

extern "C" void kernel_launch(void* const* d_in, const int* in_sizes, int n_in,
                              void* d_out, int out_size, void* d_ws, size_t ws_size,
                              hipStream_t stream) {
    const float* mapx = (const float*)d_in[0];
    const float* agt  = (const float*)d_in[1];
    const int*   u    = (const int*)d_in[2];
    const int*   v    = (const int*)d_in[3];
    const float* W0   = (const float*)d_in[4];
    const float* b0   = (const float*)d_in[5];
    const float* W1   = (const float*)d_in[6];
    const float* g1   = (const float*)d_in[7];
    const float* b1   = (const float*)d_in[8];
    const float* Wa   = (const float*)d_in[9];
    const float* g_bn = (const float*)d_in[10];
    const float* b_bn = (const float*)d_in[11];
    const float* Wf   = (const float*)d_in[12];
    const float* g_fc = (const float*)d_in[13];
    const float* b_fc = (const float*)d_in[14];
    int N = in_sizes[0] / 8;      // 500000
    int A = in_sizes[1] / 80;     // 20000
    int E = in_sizes[2];          // 500000
    float* out = (float*)d_out;

    char* ws = (char*)d_ws;
    float* P   = (float*)(ws + 0);
    float* W1T = (float*)(ws + 10240000);
    float* WfT = (float*)(ws + 10305536);
    float* WaT = (float*)(ws + 10436608);
    float* tmp = (float*)(ws + 16777216);

    transpose_w<<<(128 * 128 + 256 * 128 + 80 * 128 + 255) / 256, 256, 0, stream>>>(
        W1, Wf, Wa, W1T, WfT, WaT);
    hipMemsetAsync(tmp, 0, (size_t)N * 128 * 4, stream);
    proj_agents<<<A / 32, 256, 0, stream>>>(agt, WaT, P);
    scatter_msg<<<(int)(((long long)E * 128 + 255) / 256), 256, 0, stream>>>(P, u, v, tmp, E);
    map_fc<<<N / 32, 256, 0, stream>>>(mapx, W0, b0, W1T, g1, b1, out);   // h lives in d_out
    final_fc<<<N / 32, 256, 0, stream>>>(out, tmp, g_bn, b_bn, WfT, g_fc, b_fc, out);
}

// Round 2
// 542.776 us; speedup vs baseline: 2.4586x; 2.4586x over previous
//
#include <hip/hip_runtime.h>
#include <stdint.h>

#define EPS 1e-5f

typedef short bh8 __attribute__((ext_vector_type(8)));   // 8 bf16 in 4 VGPRs
typedef float f4v __attribute__((ext_vector_type(4)));   // MFMA accumulator

static __device__ __forceinline__ unsigned short f2bf(float f) {
    unsigned u = __builtin_bit_cast(unsigned, f);
    u += 0x7fffu + ((u >> 16) & 1u);          // RNE
    return (unsigned short)(u >> 16);
}

static __device__ __forceinline__ bh8 pack8(const float v[8]) {
    union { unsigned short s[8]; bh8 b; } u;
#pragma unroll
    for (int i = 0; i < 8; ++i) u.s[i] = f2bf(v[i]);
    return u.b;
}

// ---------------- ws layout (bytes) ----------------
// P    : 20000*128*4 = 10,240,000   @ 0
// WaT  : 80*128*4    = 40,960       @ 10,240,000
// tmp  : 500000*128*4= 256,000,000  @ 16,777,216

__global__ void wa_t(const float* __restrict__ Wa, float* __restrict__ WaT) {
    int i = blockIdx.x * 256 + threadIdx.x;
    if (i < 80 * 128) { int k = i >> 7, c = i & 127; WaT[i] = Wa[c * 80 + k]; }
}

// ---------------- P = agt_x @ Wa^T  [A x 128], K=80 (fp32, small) ----------------
__global__ __launch_bounds__(256) void proj_agents(const float* __restrict__ agt,
                                                   const float* __restrict__ WaT,
                                                   float* __restrict__ P) {
    __shared__ float WT[80 * 128];
    __shared__ float xT[80][32];
    int t = threadIdx.x;
    int row0 = blockIdx.x * 32;
#pragma unroll
    for (int m = 0; m < 40; ++m) WT[t + 256 * m] = WaT[t + 256 * m];
#pragma unroll
    for (int m = 0; m < 10; ++m) {
        int f = t + 256 * m;
        int r = f / 80, k = f - r * 80;
        xT[k][r] = agt[(size_t)(row0 + r) * 80 + k];
    }
    __syncthreads();
    int tx = t & 31, ty = t >> 5;
    float acc[4][4] = {};
    for (int k = 0; k < 80; ++k) {
        float4 xv = *(const float4*)&xT[k][ty * 4];
        float4 wv = *(const float4*)&WT[k * 128 + tx * 4];
        float xa[4] = {xv.x, xv.y, xv.z, xv.w};
        float wa[4] = {wv.x, wv.y, wv.z, wv.w};
#pragma unroll
        for (int i = 0; i < 4; ++i)
#pragma unroll
            for (int j = 0; j < 4; ++j) acc[i][j] = fmaf(xa[i], wa[j], acc[i][j]);
    }
#pragma unroll
    for (int i = 0; i < 4; ++i) {
        int r = row0 + ty * 4 + i;
        float4 o = make_float4(acc[i][0], acc[i][1], acc[i][2], acc[i][3]);
        *(float4*)&P[(size_t)r * 128 + tx * 4] = o;
    }
}

// ---------------- scatter: tmp[v[e]] += P[u[e]] ----------------
__global__ void scatter_msg(const float* __restrict__ P, const int* __restrict__ u,
                            const int* __restrict__ v, float* __restrict__ tmp, int E) {
    long long idx = (long long)blockIdx.x * 256 + threadIdx.x;
    int e = (int)(idx >> 7);
    int c = (int)(idx & 127);
    if (e < E) {
        int a = u[e], n = v[e];
        atomicAdd(&tmp[(size_t)n * 128 + c], P[(size_t)a * 128 + c]);
    }
}

// ---------------- fused: h=relu(gn(relu(x@W0^T+b0)@W1^T)); out=relu(gn([h,relu(gn(tmp))]@Wf^T))
// 32 rows/tile, 4 waves; wave w owns output cols [32w,32w+32).
// MFMA recipe (m92-verified): mfma(X,Y,C): X=[16][32] rows at lane&15, 8 k at 16B-group lg;
// Y same layout from weight rows (= output cols); D: col=lane&15, row=lg*4+reg.
__global__ __launch_bounds__(256, 2) void fused(
    const float* __restrict__ mapx, const float* __restrict__ W0,
    const float* __restrict__ b0, const float* __restrict__ W1,
    const float* __restrict__ g1, const float* __restrict__ b1,
    const float* __restrict__ tmp, const float* __restrict__ g_bn,
    const float* __restrict__ b_bn, const float* __restrict__ Wf,
    const float* __restrict__ g_fc, const float* __restrict__ b_fc,
    float* __restrict__ out, int ntiles)
{
    __shared__ __align__(16) short h0s[32 * 128];    // 8 KB, XOR-swizzled (^=(row&7)<<4)
    __shared__ __align__(16) short cats[32 * 256];   // 16 KB, XOR-swizzled
    __shared__ float W0s[128 * 8];
    __shared__ float b0s[128];
    __shared__ float part[4][32][2];
    __shared__ float statM[32], statI[32];
    __shared__ float gA[128], bA[128], gB[128], bB[128], gC[128], bC[128];

    const int t = threadIdx.x;
    const int w = t >> 6;
    const int l = t & 63;
    const int l15 = l & 15, lg = l >> 4;

    if (t < 128) {
        gA[t] = g1[t];   bA[t] = b1[t];
        gB[t] = g_bn[t]; bB[t] = b_bn[t];
        gC[t] = g_fc[t]; bC[t] = b_fc[t];
        b0s[t] = b0[t];
    }
    for (int i = t; i < 1024; i += 256) W0s[i] = W0[i];

    // weight fragments in registers (loaded once per persistent block)
    bh8 w1b[2][4], wfb[2][8];
#pragma unroll
    for (int n = 0; n < 2; ++n) {
        const int wr = 32 * w + 16 * n + l15;       // weight row = output col
#pragma unroll
        for (int s = 0; s < 4; ++s) {
            float v[8];
            const float* p = W1 + (size_t)wr * 128 + s * 32 + lg * 8;
            *(float4*)&v[0] = *(const float4*)p;
            *(float4*)&v[4] = *(const float4*)(p + 4);
            w1b[n][s] = pack8(v);
        }
#pragma unroll
        for (int s = 0; s < 8; ++s) {
            float v[8];
            const float* p = Wf + (size_t)wr * 256 + s * 32 + lg * 8;
            *(float4*)&v[0] = *(const float4*)p;
            *(float4*)&v[4] = *(const float4*)(p + 4);
            wfb[n][s] = pack8(v);
        }
    }
    __syncthreads();

    const f4v fzero = {0.f, 0.f, 0.f, 0.f};

    for (int tile = blockIdx.x; tile < ntiles; tile += (int)gridDim.x) {
        const int row0 = tile * 32;

        // --- issue tmp loads early (consumed after GEMM2) ---
        float tv[16];
        {
            const int r2 = t >> 3, c0 = (t & 7) * 16;
            const float* p = tmp + (size_t)(row0 + r2) * 128 + c0;
            *(float4*)&tv[0]  = *(const float4*)(p);
            *(float4*)&tv[4]  = *(const float4*)(p + 4);
            *(float4*)&tv[8]  = *(const float4*)(p + 8);
            *(float4*)&tv[12] = *(const float4*)(p + 12);
        }
        // --- h0 = relu(mapx@W0^T+b0) -> bf16 swizzled LDS ---
        {
            const int r = t & 31, cg = t >> 5;       // cols [16cg,16cg+16)
            float mx[8];
            const float* p = mapx + (size_t)(row0 + r) * 8;
            *(float4*)&mx[0] = *(const float4*)p;
            *(float4*)&mx[4] = *(const float4*)(p + 4);
            __align__(16) unsigned short hb[16];
#pragma unroll
            for (int c = 0; c < 16; ++c) {
                const int cc = 16 * cg + c;
                float a = b0s[cc];
#pragma unroll
                for (int j = 0; j < 8; ++j) a = fmaf(mx[j], W0s[cc * 8 + j], a);
                hb[c] = f2bf(fmaxf(a, 0.f));
            }
            const int base = r * 256 + cg * 32;
#pragma unroll
            for (int pc = 0; pc < 2; ++pc) {
                const int a = (base + 16 * pc) ^ ((r & 7) << 4);
                *(uint4*)((char*)h0s + a) = *(const uint4*)&hb[8 * pc];
            }
        }
        __syncthreads();                              // (1) h0s ready

        // --- GEMM2: h1 = h0 @ W1^T (K=128) ---
        f4v acc2[2][2];
#pragma unroll
        for (int m = 0; m < 2; ++m)
#pragma unroll
            for (int n = 0; n < 2; ++n) acc2[m][n] = fzero;
#pragma unroll
        for (int s = 0; s < 4; ++s) {
            bh8 af[2];
#pragma unroll
            for (int m = 0; m < 2; ++m) {
                const int row = 16 * m + l15;
                const int a = (row * 256 + s * 64 + lg * 16) ^ ((row & 7) << 4);
                af[m] = *(const bh8*)((const char*)h0s + a);
            }
#pragma unroll
            for (int m = 0; m < 2; ++m)
#pragma unroll
                for (int n = 0; n < 2; ++n)
                    acc2[m][n] = __builtin_amdgcn_mfma_f32_16x16x32_bf16(
                        af[m], w1b[n][s], acc2[m][n], 0, 0, 0);
        }

        // --- GN1 partials (sum over this wave's 32 cols per row) ---
#pragma unroll
        for (int m = 0; m < 2; ++m)
#pragma unroll
            for (int reg = 0; reg < 4; ++reg) {
                float a = acc2[m][0][reg] + acc2[m][1][reg];
                float q = acc2[m][0][reg] * acc2[m][0][reg] +
                          acc2[m][1][reg] * acc2[m][1][reg];
#pragma unroll
                for (int msk = 1; msk < 16; msk <<= 1) {
                    a += __shfl_xor(a, msk, 64);
                    q += __shfl_xor(q, msk, 64);
                }
                if (l15 == 0) {
                    const int row = 16 * m + 4 * lg + reg;
                    part[w][row][0] = a;
                    part[w][row][1] = q;
                }
            }
        __syncthreads();                              // (2)
        if (t < 32) {
            const float a = part[0][t][0] + part[1][t][0] + part[2][t][0] + part[3][t][0];
            const float q = part[0][t][1] + part[1][t][1] + part[2][t][1] + part[3][t][1];
            const float mean = a * (1.f / 128.f);
            const float var = q * (1.f / 128.f) - mean * mean;
            statM[t] = mean;
            statI[t] = rsqrtf(var + EPS);
        }
        __syncthreads();                              // (3)

        // --- normalized h -> cats[:,0:128] (bf16, swizzled) ---
#pragma unroll
        for (int m = 0; m < 2; ++m)
#pragma unroll
            for (int n = 0; n < 2; ++n)
#pragma unroll
                for (int reg = 0; reg < 4; ++reg) {
                    const int row = 16 * m + 4 * lg + reg;
                    const int col = 32 * w + 16 * n + l15;
                    float v2 = (acc2[m][n][reg] - statM[row]) * statI[row] * gA[col] + bA[col];
                    const int a = (row * 512 + col * 2) ^ ((row & 7) << 4);
                    *(unsigned short*)((char*)cats + a) = f2bf(fmaxf(v2, 0.f));
                }

        // --- tmp GN -> cats[:,128:256] ---
        {
            const int r2 = t >> 3, c0 = (t & 7) * 16;
            float a = 0.f, q = 0.f;
#pragma unroll
            for (int i = 0; i < 16; ++i) { a += tv[i]; q += tv[i] * tv[i]; }
#pragma unroll
            for (int msk = 1; msk < 8; msk <<= 1) {
                a += __shfl_xor(a, msk, 64);
                q += __shfl_xor(q, msk, 64);
            }
            const float mean = a * (1.f / 128.f);
            const float var = q * (1.f / 128.f) - mean * mean;
            const float inv = rsqrtf(var + EPS);
            __align__(16) unsigned short tb[16];
#pragma unroll
            for (int i = 0; i < 16; ++i) {
                const int cc = c0 + i;
                tb[i] = f2bf(fmaxf((tv[i] - mean) * inv * gB[cc] + bB[cc], 0.f));
            }
            const int base = r2 * 512 + 256 + c0 * 2;
#pragma unroll
            for (int pc = 0; pc < 2; ++pc) {
                const int ad = (base + 16 * pc) ^ ((r2 & 7) << 4);
                *(uint4*)((char*)cats + ad) = *(const uint4*)&tb[8 * pc];
            }
        }
        __syncthreads();                              // (4) cats ready

        // --- GEMM3: [h,tmp_n] @ Wf^T (K=256) ---
        f4v acc3[2][2];
#pragma unroll
        for (int m = 0; m < 2; ++m)
#pragma unroll
            for (int n = 0; n < 2; ++n) acc3[m][n] = fzero;
#pragma unroll
        for (int s = 0; s < 8; ++s) {
            bh8 af[2];
#pragma unroll
            for (int m = 0; m < 2; ++m) {
                const int row = 16 * m + l15;
                const int a = (row * 512 + s * 64 + lg * 16) ^ ((row & 7) << 4);
                af[m] = *(const bh8*)((const char*)cats + a);
            }
#pragma unroll
            for (int m = 0; m < 2; ++m)
#pragma unroll
                for (int n = 0; n < 2; ++n)
                    acc3[m][n] = __builtin_amdgcn_mfma_f32_16x16x32_bf16(
                        af[m], wfb[n][s], acc3[m][n], 0, 0, 0);
        }

        // --- GN-fc partials ---
#pragma unroll
        for (int m = 0; m < 2; ++m)
#pragma unroll
            for (int reg = 0; reg < 4; ++reg) {
                float a = acc3[m][0][reg] + acc3[m][1][reg];
                float q = acc3[m][0][reg] * acc3[m][0][reg] +
                          acc3[m][1][reg] * acc3[m][1][reg];
#pragma unroll
                for (int msk = 1; msk < 16; msk <<= 1) {
                    a += __shfl_xor(a, msk, 64);
                    q += __shfl_xor(q, msk, 64);
                }
                if (l15 == 0) {
                    const int row = 16 * m + 4 * lg + reg;
                    part[w][row][0] = a;
                    part[w][row][1] = q;
                }
            }
        __syncthreads();                              // (5)
        if (t < 32) {
            const float a = part[0][t][0] + part[1][t][0] + part[2][t][0] + part[3][t][0];
            const float q = part[0][t][1] + part[1][t][1] + part[2][t][1] + part[3][t][1];
            const float mean = a * (1.f / 128.f);
            const float var = q * (1.f / 128.f) - mean * mean;
            statM[t] = mean;
            statI[t] = rsqrtf(var + EPS);
        }
        __syncthreads();                              // (6)

        // --- epilogue: GN+ReLU, store fp32 ---
#pragma unroll
        for (int m = 0; m < 2; ++m)
#pragma unroll
            for (int n = 0; n < 2; ++n)
#pragma unroll
                for (int reg = 0; reg < 4; ++reg) {
                    const int row = 16 * m + 4 * lg + reg;
                    const int col = 32 * w + 16 * n + l15;
                    float v3 = (acc3[m][n][reg] - statM[row]) * statI[row] * gC[col] + bC[col];
                    out[(size_t)(row0 + row) * 128 + col] = fmaxf(v3, 0.f);
                }
    }
}

extern "C" void kernel_launch(void* const* d_in, const int* in_sizes, int n_in,
                              void* d_out, int out_size, void* d_ws, size_t ws_size,
                              hipStream_t stream) {
    const float* mapx = (const float*)d_in[0];
    const float* agt  = (const float*)d_in[1];
    const int*   u    = (const int*)d_in[2];
    const int*   v    = (const int*)d_in[3];
    const float* W0   = (const float*)d_in[4];
    const float* b0   = (const float*)d_in[5];
    const float* W1   = (const float*)d_in[6];
    const float* g1   = (const float*)d_in[7];
    const float* b1   = (const float*)d_in[8];
    const float* Wa   = (const float*)d_in[9];
    const float* g_bn = (const float*)d_in[10];
    const float* b_bn = (const float*)d_in[11];
    const float* Wf   = (const float*)d_in[12];
    const float* g_fc = (const float*)d_in[13];
    const float* b_fc = (const float*)d_in[14];
    int N = in_sizes[0] / 8;      // 500000
    int A = in_sizes[1] / 80;     // 20000
    int E = in_sizes[2];          // 500000
    float* out = (float*)d_out;

    char* ws = (char*)d_ws;
    float* P   = (float*)(ws + 0);
    float* WaT = (float*)(ws + 10240000);
    float* tmp = (float*)(ws + 16777216);

    wa_t<<<40, 256, 0, stream>>>(Wa, WaT);
    hipMemsetAsync(tmp, 0, (size_t)N * 128 * 4, stream);
    proj_agents<<<A / 32, 256, 0, stream>>>(agt, WaT, P);
    scatter_msg<<<(int)(((long long)E * 128 + 255) / 256), 256, 0, stream>>>(P, u, v, tmp, E);
    int ntiles = N / 32;          // 15625 exact
    fused<<<512, 256, 0, stream>>>(mapx, W0, b0, W1, g1, b1, tmp, g_bn, b_bn,
                                   Wf, g_fc, b_fc, out, ntiles);
}

// Round 3
// 450.982 us; speedup vs baseline: 2.9590x; 1.2035x over previous
//
#include <hip/hip_runtime.h>
#include <stdint.h>

#define EPS 1e-5f

typedef short bh8 __attribute__((ext_vector_type(8)));   // 8 bf16 in 4 VGPRs
typedef float f4v __attribute__((ext_vector_type(4)));   // MFMA accumulator

static __device__ __forceinline__ unsigned short f2bf(float f) {
    unsigned u = __builtin_bit_cast(unsigned, f);
    u += 0x7fffu + ((u >> 16) & 1u);          // RNE
    return (unsigned short)(u >> 16);
}

static __device__ __forceinline__ bh8 pack8(const float v[8]) {
    union { unsigned short s[8]; bh8 b; } u;
#pragma unroll
    for (int i = 0; i < 8; ++i) u.s[i] = f2bf(v[i]);
    return u.b;
}

static __device__ __forceinline__ float bfbits(unsigned x) {   // low/high half picked by caller
    return __builtin_bit_cast(float, x);
}

// ---------------- ws layout (bytes) ----------------
// Pb      (bf16) : 0          .. 5,120,000
// WaT     (f32)  : 5,120,000  .. 5,160,960
// cnt     (int)  : 5,160,960  .. 7,160,960   \ one 4MB memset
// cursor  (int)  : 7,160,960  .. 9,160,960   /
// rp      (int)  : 9,160,960  .. 11,160,964  (N+1)
// partials(int)  : 11,161,024 .. 11,163,072
// col     (int)  : 11,163,072 .. 13,163,072

__global__ void wa_t(const float* __restrict__ Wa, float* __restrict__ WaT) {
    int i = blockIdx.x * 256 + threadIdx.x;
    if (i < 80 * 128) { int k = i >> 7, c = i & 127; WaT[i] = Wa[c * 80 + k]; }
}

// ---------------- P = agt_x @ Wa^T  [A x 128] bf16 out, K=80 ----------------
__global__ __launch_bounds__(256) void proj_agents(const float* __restrict__ agt,
                                                   const float* __restrict__ WaT,
                                                   unsigned short* __restrict__ Pb) {
    __shared__ float WT[80 * 128];
    __shared__ float xT[80][32];
    int t = threadIdx.x;
    int row0 = blockIdx.x * 32;
#pragma unroll
    for (int m = 0; m < 40; ++m) WT[t + 256 * m] = WaT[t + 256 * m];
#pragma unroll
    for (int m = 0; m < 10; ++m) {
        int f = t + 256 * m;
        int r = f / 80, k = f - r * 80;
        xT[k][r] = agt[(size_t)(row0 + r) * 80 + k];
    }
    __syncthreads();
    int tx = t & 31, ty = t >> 5;
    float acc[4][4] = {};
    for (int k = 0; k < 80; ++k) {
        float4 xv = *(const float4*)&xT[k][ty * 4];
        float4 wv = *(const float4*)&WT[k * 128 + tx * 4];
        float xa[4] = {xv.x, xv.y, xv.z, xv.w};
        float wa[4] = {wv.x, wv.y, wv.z, wv.w};
#pragma unroll
        for (int i = 0; i < 4; ++i)
#pragma unroll
            for (int j = 0; j < 4; ++j) acc[i][j] = fmaf(xa[i], wa[j], acc[i][j]);
    }
#pragma unroll
    for (int i = 0; i < 4; ++i) {
        int r = row0 + ty * 4 + i;
        union { unsigned short s[4]; uint2 q; } o;
#pragma unroll
        for (int j = 0; j < 4; ++j) o.s[j] = f2bf(acc[i][j]);
        *(uint2*)&Pb[(size_t)r * 128 + tx * 4] = o.q;
    }
}

// ---------------- CSR build ----------------
__global__ void hist_v(const int* __restrict__ v, int* __restrict__ cnt, int E) {
    int e = blockIdx.x * 256 + threadIdx.x;
    if (e < E) atomicAdd(&cnt[v[e]], 1);
}

// block-local exclusive scan over 4096 elements; writes local prefix + block total
__global__ __launch_bounds__(256) void scan1(const int* __restrict__ cnt,
                                             int* __restrict__ rp,
                                             int* __restrict__ partials, int n) {
    __shared__ int lds[256];
    int b = blockIdx.x, t = threadIdx.x;
    int base = b * 4096 + t * 16;
    int vv[16];
    int run = 0;
#pragma unroll
    for (int i = 0; i < 16; ++i) {
        int c = (base + i < n) ? cnt[base + i] : 0;
        vv[i] = run;
        run += c;
    }
    lds[t] = run;
    __syncthreads();
#pragma unroll
    for (int off = 1; off < 256; off <<= 1) {
        int x = (t >= off) ? lds[t - off] : 0;
        __syncthreads();
        lds[t] += x;
        __syncthreads();
    }
    int excl = lds[t] - run;                 // prefix of threads before t
    if (t == 255) partials[b] = lds[255];
#pragma unroll
    for (int i = 0; i < 16; ++i)
        if (base + i < n) rp[base + i] = excl + vv[i];
}

__global__ __launch_bounds__(256) void scan2(int* __restrict__ partials, int nb) {
    __shared__ int lds[256];
    int t = threadIdx.x;
    int vv = (t < nb) ? partials[t] : 0;
    lds[t] = vv;
    __syncthreads();
#pragma unroll
    for (int off = 1; off < 256; off <<= 1) {
        int x = (t >= off) ? lds[t - off] : 0;
        __syncthreads();
        lds[t] += x;
        __syncthreads();
    }
    if (t < nb) partials[t] = lds[t] - vv;   // exclusive block offsets
}

__global__ void scan3(int* __restrict__ rp, const int* __restrict__ partials,
                      int n, int E) {
    int i = blockIdx.x * 256 + threadIdx.x;
    if (i < n) rp[i] += partials[i >> 12];
    if (i == 0) rp[n] = E;
}

__global__ void fill_csr(const int* __restrict__ u, const int* __restrict__ v,
                         const int* __restrict__ rp, int* __restrict__ cursor,
                         int* __restrict__ col, int E) {
    int e = blockIdx.x * 256 + threadIdx.x;
    if (e < E) {
        int vv = v[e];
        int pos = rp[vv] + atomicAdd(&cursor[vv], 1);
        col[pos] = u[e];
    }
}

// ---------------- fused: h=relu(gn(relu(x@W0^T+b0)@W1^T));
//                  out=relu(gn([h, relu(gn(Σ_edges P[u]))]@Wf^T))
// 32 rows/tile, 4 waves; wave w owns output cols [32w,32w+32).
// MFMA operands SWAPPED: acc[m][n] = mfma(Wfrag[n], Xfrag[m], acc):
//   D col = lane&15 = data row (16m+l15); D row = 4*lg+reg = output col (32w+16n+4lg+reg)
//   -> float4 stores, 8B cats writes, row stats live on l15 lanes.
__global__ __launch_bounds__(256, 3) void fused(
    const float* __restrict__ mapx, const float* __restrict__ W0,
    const float* __restrict__ b0, const float* __restrict__ W1,
    const float* __restrict__ g1, const float* __restrict__ b1,
    const unsigned short* __restrict__ Pb, const int* __restrict__ rp,
    const int* __restrict__ col, const float* __restrict__ g_bn,
    const float* __restrict__ b_bn, const float* __restrict__ Wf,
    const float* __restrict__ g_fc, const float* __restrict__ b_fc,
    float* __restrict__ out, int ntiles)
{
    __shared__ __align__(16) short h0s[32 * 128];    // 8 KB, XOR-swizzled (^=(row&7)<<4)
    __shared__ __align__(16) short cats[32 * 256];   // 16 KB, XOR-swizzled
    __shared__ float W0s[128 * 8];
    __shared__ float b0s[128];
    __shared__ float2 part[4][32];                   // per-wave GN partials (sum, sumsq)
    __shared__ float gA[128], bA[128], gB[128], bB[128], gC[128], bC[128];

    const int t = threadIdx.x;
    const int w = t >> 6;
    const int l = t & 63;
    const int l15 = l & 15, lg = l >> 4;

    if (t < 128) {
        gA[t] = g1[t];   bA[t] = b1[t];
        gB[t] = g_bn[t]; bB[t] = b_bn[t];
        gC[t] = g_fc[t]; bC[t] = b_fc[t];
        b0s[t] = b0[t];
    }
    for (int i = t; i < 1024; i += 256) W0s[i] = W0[i];

    // weight fragments in registers (persistent)
    bh8 w1b[2][4], wfb[2][8];
#pragma unroll
    for (int n = 0; n < 2; ++n) {
        const int wr = 32 * w + 16 * n + l15;        // weight row = output col
#pragma unroll
        for (int s = 0; s < 4; ++s) {
            float vv[8];
            const float* p = W1 + (size_t)wr * 128 + s * 32 + lg * 8;
            *(float4*)&vv[0] = *(const float4*)p;
            *(float4*)&vv[4] = *(const float4*)(p + 4);
            w1b[n][s] = pack8(vv);
        }
#pragma unroll
        for (int s = 0; s < 8; ++s) {
            float vv[8];
            const float* p = Wf + (size_t)wr * 256 + s * 32 + lg * 8;
            *(float4*)&vv[0] = *(const float4*)p;
            *(float4*)&vv[4] = *(const float4*)(p + 4);
            wfb[n][s] = pack8(vv);
        }
    }
    __syncthreads();

    const f4v fzero = {0.f, 0.f, 0.f, 0.f};

    for (int tile = blockIdx.x; tile < ntiles; tile += (int)gridDim.x) {
        const int row0 = tile * 32;

        // --- gather messages: tv = Σ_{e: v==row} P[u[e]]  (8 threads/row, 16 ch each) ---
        const int r2 = t >> 3, c0 = (t & 7) * 16;
        float tv[16] = {};
        {
            const int beg = rp[row0 + r2], end = rp[row0 + r2 + 1];
            for (int j = beg; j < end; ++j) {
                const int a = col[j];
                const unsigned short* pr = Pb + (size_t)a * 128 + c0;
                uint4 q0 = *(const uint4*)pr;
                uint4 q1 = *(const uint4*)(pr + 8);
                unsigned qa[8] = {q0.x, q0.y, q0.z, q0.w, q1.x, q1.y, q1.z, q1.w};
#pragma unroll
                for (int p2 = 0; p2 < 8; ++p2) {
                    tv[p2 * 2 + 0] += bfbits(qa[p2] << 16);
                    tv[p2 * 2 + 1] += bfbits(qa[p2] & 0xffff0000u);
                }
            }
        }

        // --- h0 = relu(mapx@W0^T+b0) -> bf16 swizzled LDS ---
        {
            const int r = t & 31, cg = t >> 5;       // cols [16cg,16cg+16)
            float mx[8];
            const float* p = mapx + (size_t)(row0 + r) * 8;
            *(float4*)&mx[0] = *(const float4*)p;
            *(float4*)&mx[4] = *(const float4*)(p + 4);
            __align__(16) unsigned short hb[16];
#pragma unroll
            for (int c = 0; c < 16; ++c) {
                const int cc = 16 * cg + c;
                float a = b0s[cc];
#pragma unroll
                for (int j = 0; j < 8; ++j) a = fmaf(mx[j], W0s[cc * 8 + j], a);
                hb[c] = f2bf(fmaxf(a, 0.f));
            }
            const int base = r * 256 + cg * 32;
#pragma unroll
            for (int pc = 0; pc < 2; ++pc) {
                const int a = (base + 16 * pc) ^ ((r & 7) << 4);
                *(uint4*)((char*)h0s + a) = *(const uint4*)&hb[8 * pc];
            }
        }
        __syncthreads();                              // (1) h0s ready

        // --- GEMM2: h1 = h0 @ W1^T (K=128), transposed acc ---
        f4v acc2[2][2];
#pragma unroll
        for (int m = 0; m < 2; ++m)
#pragma unroll
            for (int n = 0; n < 2; ++n) acc2[m][n] = fzero;
#pragma unroll
        for (int s = 0; s < 4; ++s) {
            bh8 af[2];
#pragma unroll
            for (int m = 0; m < 2; ++m) {
                const int row = 16 * m + l15;
                const int a = (row * 256 + s * 64 + lg * 16) ^ ((row & 7) << 4);
                af[m] = *(const bh8*)((const char*)h0s + a);
            }
#pragma unroll
            for (int m = 0; m < 2; ++m)
#pragma unroll
                for (int n = 0; n < 2; ++n)
                    acc2[m][n] = __builtin_amdgcn_mfma_f32_16x16x32_bf16(
                        w1b[n][s], af[m], acc2[m][n], 0, 0, 0);
        }

        // --- GN1 partials: row = 16m+l15 lives on l15 lanes; reduce across lg ---
#pragma unroll
        for (int m = 0; m < 2; ++m) {
            float a = 0.f, q = 0.f;
#pragma unroll
            for (int n = 0; n < 2; ++n)
#pragma unroll
                for (int reg = 0; reg < 4; ++reg) {
                    float x = acc2[m][n][reg];
                    a += x; q += x * x;
                }
            a += __shfl_xor(a, 16, 64); q += __shfl_xor(q, 16, 64);
            a += __shfl_xor(a, 32, 64); q += __shfl_xor(q, 32, 64);
            if (lg == 0) part[w][16 * m + l15] = make_float2(a, q);
        }
        __syncthreads();                              // (2) part ready

        // per-thread GN1 stats for rows {l15, 16+l15}
        float meanA[2], invA[2];
#pragma unroll
        for (int m = 0; m < 2; ++m) {
            const int row = 16 * m + l15;
            float2 p0 = part[0][row], p1 = part[1][row];
            float2 p2 = part[2][row], p3 = part[3][row];
            float a = p0.x + p1.x + p2.x + p3.x;
            float q = p0.y + p1.y + p2.y + p3.y;
            float mean = a * (1.f / 128.f);
            float var = q * (1.f / 128.f) - mean * mean;
            meanA[m] = mean;
            invA[m] = rsqrtf(var + EPS);
        }

        // --- normalized h -> cats[:,0:128] (8B writes) ---
#pragma unroll
        for (int m = 0; m < 2; ++m) {
            const int row = 16 * m + l15;
#pragma unroll
            for (int n = 0; n < 2; ++n) {
                const int c00 = 32 * w + 16 * n + 4 * lg;
                union { unsigned short s[4]; uint2 q; } o;
#pragma unroll
                for (int reg = 0; reg < 4; ++reg) {
                    float v2 = (acc2[m][n][reg] - meanA[m]) * invA[m] * gA[c00 + reg] + bA[c00 + reg];
                    o.s[reg] = f2bf(fmaxf(v2, 0.f));
                }
                const int a = (row * 512 + c00 * 2) ^ ((row & 7) << 4);
                *(uint2*)((char*)cats + a) = o.q;
            }
        }

        // --- message GN -> cats[:,128:256] ---
        {
            float a = 0.f, q = 0.f;
#pragma unroll
            for (int i = 0; i < 16; ++i) { a += tv[i]; q += tv[i] * tv[i]; }
#pragma unroll
            for (int msk = 1; msk < 8; msk <<= 1) {
                a += __shfl_xor(a, msk, 64);
                q += __shfl_xor(q, msk, 64);
            }
            const float mean = a * (1.f / 128.f);
            const float var = q * (1.f / 128.f) - mean * mean;
            const float inv = rsqrtf(var + EPS);
            __align__(16) unsigned short tb[16];
#pragma unroll
            for (int i = 0; i < 16; ++i) {
                const int cc = c0 + i;
                tb[i] = f2bf(fmaxf((tv[i] - mean) * inv * gB[cc] + bB[cc], 0.f));
            }
            const int base = r2 * 512 + 256 + c0 * 2;
#pragma unroll
            for (int pc = 0; pc < 2; ++pc) {
                const int ad = (base + 16 * pc) ^ ((r2 & 7) << 4);
                *(uint4*)((char*)cats + ad) = *(const uint4*)&tb[8 * pc];
            }
        }
        __syncthreads();                              // (3) cats ready

        // --- GEMM3: [h,msg_n] @ Wf^T (K=256) ---
        f4v acc3[2][2];
#pragma unroll
        for (int m = 0; m < 2; ++m)
#pragma unroll
            for (int n = 0; n < 2; ++n) acc3[m][n] = fzero;
#pragma unroll
        for (int s = 0; s < 8; ++s) {
            bh8 af[2];
#pragma unroll
            for (int m = 0; m < 2; ++m) {
                const int row = 16 * m + l15;
                const int a = (row * 512 + s * 64 + lg * 16) ^ ((row & 7) << 4);
                af[m] = *(const bh8*)((const char*)cats + a);
            }
#pragma unroll
            for (int m = 0; m < 2; ++m)
#pragma unroll
                for (int n = 0; n < 2; ++n)
                    acc3[m][n] = __builtin_amdgcn_mfma_f32_16x16x32_bf16(
                        wfb[n][s], af[m], acc3[m][n], 0, 0, 0);
        }

        // --- GN-fc partials ---
#pragma unroll
        for (int m = 0; m < 2; ++m) {
            float a = 0.f, q = 0.f;
#pragma unroll
            for (int n = 0; n < 2; ++n)
#pragma unroll
                for (int reg = 0; reg < 4; ++reg) {
                    float x = acc3[m][n][reg];
                    a += x; q += x * x;
                }
            a += __shfl_xor(a, 16, 64); q += __shfl_xor(q, 16, 64);
            a += __shfl_xor(a, 32, 64); q += __shfl_xor(q, 32, 64);
            if (lg == 0) part[w][16 * m + l15] = make_float2(a, q);
        }
        __syncthreads();                              // (4) part ready

        // --- epilogue: per-thread stats, GN+ReLU, float4 store ---
#pragma unroll
        for (int m = 0; m < 2; ++m) {
            const int row = 16 * m + l15;
            float2 p0 = part[0][row], p1 = part[1][row];
            float2 p2 = part[2][row], p3 = part[3][row];
            float a = p0.x + p1.x + p2.x + p3.x;
            float q = p0.y + p1.y + p2.y + p3.y;
            float mean = a * (1.f / 128.f);
            float var = q * (1.f / 128.f) - mean * mean;
            float inv = rsqrtf(var + EPS);
#pragma unroll
            for (int n = 0; n < 2; ++n) {
                const int c00 = 32 * w + 16 * n + 4 * lg;
                float4 o;
                o.x = fmaxf((acc3[m][n][0] - mean) * inv * gC[c00 + 0] + bC[c00 + 0], 0.f);
                o.y = fmaxf((acc3[m][n][1] - mean) * inv * gC[c00 + 1] + bC[c00 + 1], 0.f);
                o.z = fmaxf((acc3[m][n][2] - mean) * inv * gC[c00 + 2] + bC[c00 + 2], 0.f);
                o.w = fmaxf((acc3[m][n][3] - mean) * inv * gC[c00 + 3] + bC[c00 + 3], 0.f);
                *(float4*)&out[(size_t)(row0 + row) * 128 + c00] = o;
            }
        }
    }
}

extern "C" void kernel_launch(void* const* d_in, const int* in_sizes, int n_in,
                              void* d_out, int out_size, void* d_ws, size_t ws_size,
                              hipStream_t stream) {
    const float* mapx = (const float*)d_in[0];
    const float* agt  = (const float*)d_in[1];
    const int*   u    = (const int*)d_in[2];
    const int*   v    = (const int*)d_in[3];
    const float* W0   = (const float*)d_in[4];
    const float* b0   = (const float*)d_in[5];
    const float* W1   = (const float*)d_in[6];
    const float* g1   = (const float*)d_in[7];
    const float* b1   = (const float*)d_in[8];
    const float* Wa   = (const float*)d_in[9];
    const float* g_bn = (const float*)d_in[10];
    const float* b_bn = (const float*)d_in[11];
    const float* Wf   = (const float*)d_in[12];
    const float* g_fc = (const float*)d_in[13];
    const float* b_fc = (const float*)d_in[14];
    int N = in_sizes[0] / 8;      // 500000
    int A = in_sizes[1] / 80;     // 20000
    int E = in_sizes[2];          // 500000
    float* out = (float*)d_out;

    char* ws = (char*)d_ws;
    unsigned short* Pb  = (unsigned short*)(ws + 0);
    float* WaT          = (float*)(ws + 5120000);
    int*   cnt          = (int*)(ws + 5160960);
    int*   cursor       = (int*)(ws + 7160960);
    int*   rp           = (int*)(ws + 9160960);
    int*   partials     = (int*)(ws + 11161024);
    int*   colv         = (int*)(ws + 11163072);

    const int nb_scan = (N + 4095) / 4096;           // 123
    const int nb_e = (E + 255) / 256;

    wa_t<<<40, 256, 0, stream>>>(Wa, WaT);
    hipMemsetAsync(cnt, 0, 4000000, stream);          // cnt + cursor
    hist_v<<<nb_e, 256, 0, stream>>>(v, cnt, E);
    proj_agents<<<A / 32, 256, 0, stream>>>(agt, WaT, Pb);
    scan1<<<nb_scan, 256, 0, stream>>>(cnt, rp, partials, N);
    scan2<<<1, 256, 0, stream>>>(partials, nb_scan);
    scan3<<<(N + 255) / 256, 256, 0, stream>>>(rp, partials, N, E);
    fill_csr<<<nb_e, 256, 0, stream>>>(u, v, rp, cursor, colv, E);

    int ntiles = N / 32;          // 15625 exact
    fused<<<768, 256, 0, stream>>>(mapx, W0, b0, W1, g1, b1, Pb, rp, colv,
                                   g_bn, b_bn, Wf, g_fc, b_fc, out, ntiles);
}